// Round 2
// baseline (259.885 us; speedup 1.0000x reference)
//
#include <hip/hip_runtime.h>
#include <hip/hip_bf16.h>

typedef __attribute__((ext_vector_type(8))) short short8;
typedef __attribute__((ext_vector_type(4))) short short4v;
typedef __attribute__((ext_vector_type(4))) float float4v;

#define DIM   1024
#define NH    16
#define HD    64
#define BSZ   4
#define TSZ   2048
#define BT    (BSZ*TSZ)   // 8192

// P row stride (elems): 72 = 9*16B rows -> spread bank groups for b128 reads
#define PSTR  72

// softmax exponent bias: |s| <= |q||k|*0.18 ~ 12 << 24; exp2(s-24) never
// overflows, never fully underflows (needs s < -102). Softmax shift-invariant
// -> dividing by lsum reproduces reference exactly. Kills online rescaling.
// Crucially: partials are LINEAR -> causal k-range can be split across blocks
// and merged as O = (O0+O1)/(l0+l1) with no max bookkeeping.
#define SBIAS 24.0f

typedef const __attribute__((address_space(1))) void* gptr_t;
typedef __attribute__((address_space(3))) void* lptr_t;

__device__ __forceinline__ short f2bs(float x) {
    __hip_bfloat16 h = __float2bfloat16(x);
    return __builtin_bit_cast(short, h);
}

// ---------------------------------------------------------------------------
// fp32 -> bf16 conversion: x (8192 blocks) + wq/wk/wv/wo (1024 blocks each).
// ---------------------------------------------------------------------------
__global__ __launch_bounds__(256) void cvt_kernel(
    const float* __restrict__ x,  const float* __restrict__ wq,
    const float* __restrict__ wk, const float* __restrict__ wv,
    const float* __restrict__ wo,
    __hip_bfloat16* __restrict__ xb,  __hip_bfloat16* __restrict__ wqb,
    __hip_bfloat16* __restrict__ wkb, __hip_bfloat16* __restrict__ wvb,
    __hip_bfloat16* __restrict__ wob)
{
    int bid = blockIdx.x;
    const float* src; __hip_bfloat16* dst; int base;
    if (bid < 8192) { src = x; dst = xb; base = bid; }
    else {
        int wsel = (bid - 8192) >> 10;
        base = (bid - 8192) & 1023;
        src = (wsel == 0) ? wq : (wsel == 1) ? wk : (wsel == 2) ? wv : wo;
        dst = (wsel == 0) ? wqb : (wsel == 1) ? wkb : (wsel == 2) ? wvb : wob;
    }
    size_t off = (size_t)base * 1024 + threadIdx.x * 4;
    float4v v = *(const float4v*)(src + off);
    short4v o;
    o[0] = f2bs(v[0]); o[1] = f2bs(v[1]); o[2] = f2bs(v[2]); o[3] = f2bs(v[3]);
    *(short4v*)((short*)dst + off) = o;
}

// ---------------------------------------------------------------------------
// gemm_core v2: 128x128 tile, BK=64 (16 iters, 32 MFMA/barrier), XOR-swizzled
// staging so ds_read_b128 frag reads are 2-way (free) instead of 8-way.
// ---------------------------------------------------------------------------
__device__ __forceinline__ void gemm_core(
    const __hip_bfloat16* __restrict__ A,
    const __hip_bfloat16* __restrict__ B,
    __hip_bfloat16* smA, __hip_bfloat16* smB,
    int m0, int n0, int tid, float4v acc[4][4])
{
    const int wid = tid >> 6, lane = tid & 63;
    const int quad = lane >> 4, l15 = lane & 15;
    const int l7 = l15 & 7;
    const int wm = (wid >> 1) * 64, wn = (wid & 1) * 64;
    const int srow = tid >> 3;                        // 0..31
    const int scol = ((tid & 7) ^ (srow & 7)) * 8;    // swizzled source chunk

    const __hip_bfloat16* gA0 = A + (size_t)(m0 + srow) * DIM + scol;
    const __hip_bfloat16* gB0 = B + (size_t)(n0 + srow) * DIM + scol;

    for (int kc = 0; kc < DIM; kc += 64) {
        __syncthreads();
#pragma unroll
        for (int j = 0; j < 4; j++) {
            __builtin_amdgcn_global_load_lds((gptr_t)(gA0 + (size_t)(j*32)*DIM + kc),
                (lptr_t)(smA + j*2048 + tid*8), 16, 0, 0);
            __builtin_amdgcn_global_load_lds((gptr_t)(gB0 + (size_t)(j*32)*DIM + kc),
                (lptr_t)(smB + j*2048 + tid*8), 16, 0, 0);
        }
        __syncthreads();

#pragma unroll
        for (int s = 0; s < 2; s++) {
            short8 a[4], b[4];
#pragma unroll
            for (int mb = 0; mb < 4; mb++)
                a[mb] = *(const short8*)(smA + (wm + mb*16 + l15)*64 + ((s*4 + quad) ^ l7)*8);
#pragma unroll
            for (int nb = 0; nb < 4; nb++)
                b[nb] = *(const short8*)(smB + (wn + nb*16 + l15)*64 + ((s*4 + quad) ^ l7)*8);
#pragma unroll
            for (int mb = 0; mb < 4; mb++)
#pragma unroll
                for (int nb = 0; nb < 4; nb++)
                    acc[mb][nb] = __builtin_amdgcn_mfma_f32_16x16x32_bf16(
                        a[mb], b[nb], acc[mb][nb], 0, 0, 0);
        }
    }
}

// ---------------------------------------------------------------------------
// QKV projection. Q pre-scaled by 0.125*log2(e) -> softmax in exp2 domain.
// ---------------------------------------------------------------------------
__global__ __launch_bounds__(256) void qkv_gemm(
    const __hip_bfloat16* __restrict__ xb,
    const __hip_bfloat16* __restrict__ wqb,
    const __hip_bfloat16* __restrict__ wkb,
    const __hip_bfloat16* __restrict__ wvb,
    __hip_bfloat16* __restrict__ Qb,
    __hip_bfloat16* __restrict__ Kb,
    __hip_bfloat16* __restrict__ Vt)
{
    __shared__ __hip_bfloat16 smA[128*64];
    __shared__ __hip_bfloat16 smB[128*64];

    const int z = blockIdx.z;
    const __hip_bfloat16* w = (z == 0) ? wqb : ((z == 1) ? wkb : wvb);
    const int tid = threadIdx.x;
    const int wid = tid >> 6, lane = tid & 63;
    const int quad = lane >> 4, l15 = lane & 15;
    const int m0 = blockIdx.x * 128, n0 = blockIdx.y * 128;
    const int wm0 = m0 + (wid >> 1) * 64;
    const int wn0 = n0 + (wid & 1) * 64;
    const float qscale = 0.1803368801111204f;  // 0.125 * log2(e)

    float4v acc[4][4];
#pragma unroll
    for (int i = 0; i < 4; i++)
#pragma unroll
        for (int j = 0; j < 4; j++)
#pragma unroll
            for (int r = 0; r < 4; r++) acc[i][j][r] = 0.0f;

    gemm_core(xb, w, smA, smB, m0, n0, tid, acc);

    if (z == 2) {
        const int h = wn0 >> 6;
#pragma unroll
        for (int mb = 0; mb < 4; mb++) {
            int m = wm0 + mb*16 + quad*4;
            int bb = m >> 11, t0 = m & 2047;
#pragma unroll
            for (int nb = 0; nb < 4; nb++) {
                int d = nb*16 + l15;
                short4v pk;
                pk[0] = f2bs(acc[mb][nb][0]); pk[1] = f2bs(acc[mb][nb][1]);
                pk[2] = f2bs(acc[mb][nb][2]); pk[3] = f2bs(acc[mb][nb][3]);
                *(short4v*)(Vt + (size_t)((bb*NH + h)*HD + d)*TSZ + t0) = pk;
            }
        }
    } else {
        const float sc = (z == 0) ? qscale : 1.0f;
        __hip_bfloat16* dst = (z == 0) ? Qb : Kb;
#pragma unroll
        for (int mb = 0; mb < 4; mb++)
#pragma unroll
            for (int r = 0; r < 4; r++) {
                int m = wm0 + mb*16 + quad*4 + r;
                int bb = m >> 11, t = m & 2047;
#pragma unroll
                for (int nb = 0; nb < 4; nb++) {
                    int n = wn0 + nb*16 + l15;
                    int h = n >> 6, d = n & 63;
                    dst[(size_t)((bb*NH + h)*TSZ + t)*HD + d] =
                        __float2bfloat16(acc[mb][nb][r] * sc);
                }
            }
    }
}

// ---------------------------------------------------------------------------
// Causal flash attention v5: fixed-bias softmax + BALANCED K-SPLIT JOBS.
//
// Old v4: grid (64 bh, 16 qt). All 1024 blocks co-resident (4/CU), work per
// block = 2*qt+2 k-tiles (2..32, 16x spread) -> occupancy decays 50%->~8%,
// time-avg 26%, critical path = 32 sequential k-steps of the qt=15 block,
// while the kernel is VALU/trans-issue bound per wave. Fix: q-tiles qt>=8
// are split into two half-k-range jobs of (qt+1) tiles each (fixed-bias
// softmax partials are linear: O=(O0+O1)/(l0+l1)). 24 jobs/bh, lengths
// 16,16,16,15,15,...,2 dispatched heavy-first. Critical path 32 -> 16 steps.
// Half jobs write unnormalized fp32 partials + lsum; attn_merge combines.
// ---------------------------------------------------------------------------
static __device__ const int jqt[24]  = {15,15, 7,14,14,13,13, 6,12,12,11,11, 5,10,10, 9, 9, 4, 8, 8, 3, 2, 1, 0};
static __device__ const int jkb[24]  = { 0,16, 0, 0,15, 0,14, 0, 0,13, 0,12, 0, 0,11, 0,10, 0, 0, 9, 0, 0, 0, 0};
static __device__ const int jke[24]  = {16,32,16,15,30,14,28,14,13,26,12,24,12,11,22,10,20,10, 9,18, 8, 6, 4, 2};
static __device__ const int jpart[24]= { 0, 1,-1, 0, 1, 0, 1,-1, 0, 1, 0, 1,-1, 0, 1, 0, 1,-1, 0, 1,-1,-1,-1,-1};

__global__ __launch_bounds__(256, 2) void attn_split(
    const __hip_bfloat16* __restrict__ Qb,
    const __hip_bfloat16* __restrict__ Kb,
    const __hip_bfloat16* __restrict__ Vt,
    __hip_bfloat16* __restrict__ Ob,
    float* __restrict__ POb,      // [64*8][2][128][64] fp32 partial O
    float* __restrict__ PLs)      // [64*8][2][128]     fp32 partial lsum
{
    __shared__ __hip_bfloat16 smK[64*64];       // [k-row][d], XOR-swizzled chunks
    __shared__ __hip_bfloat16 smV[64*64];       // [d][t],     XOR-swizzled chunks
    __shared__ __hip_bfloat16 Pl[4][32*PSTR];   // per-wave P (4.6KB each)

    const int bh = blockIdx.x;
    const int jy = blockIdx.y;
    const int qt = jqt[jy];
    const int kb = jkb[jy], ke = jke[jy];
    const int part = jpart[jy];
    const int q0 = qt * 128;
    const int tid = threadIdx.x;
    const int wid = tid >> 6, lane = tid & 63;
    const int quad = lane >> 4, l15 = lane & 15;
    const int l7 = l15 & 7;
    const int q0w = q0 + wid * 32;

    const __hip_bfloat16* Qp = Qb + (size_t)bh * TSZ * HD;
    const __hip_bfloat16* Kp = Kb + (size_t)bh * TSZ * HD;
    const __hip_bfloat16* Vp = Vt + (size_t)bh * HD * TSZ;
    __hip_bfloat16* P = &Pl[wid][0];

    const int srow = tid >> 3;
    const int scol = ((tid & 7) ^ (srow & 7)) * 8;

    short8 bq[2][2];
#pragma unroll
    for (int nt = 0; nt < 2; nt++)
#pragma unroll
        for (int c = 0; c < 2; c++)
            bq[nt][c] = *(const short8*)(Qp + (size_t)(q0w + nt*16 + l15)*HD + c*32 + quad*8);

    float lsum[2] = {0.f, 0.f};
    float4v ot[4][2];
#pragma unroll
    for (int mt = 0; mt < 4; mt++)
#pragma unroll
        for (int nt = 0; nt < 2; nt++)
#pragma unroll
            for (int r = 0; r < 4; r++) ot[mt][nt][r] = 0.f;

    for (int it = kb; it < ke; ++it) {
        const int k0 = it * 64;

        __syncthreads();
#pragma unroll
        for (int c = 0; c < 2; c++) {
            __builtin_amdgcn_global_load_lds(
                (gptr_t)(Kp + (size_t)(k0 + srow + 32*c)*HD + scol),
                (lptr_t)(smK + tid*8 + c*2048), 16, 0, 0);
            __builtin_amdgcn_global_load_lds(
                (gptr_t)(Vp + (size_t)(srow + 32*c)*TSZ + k0 + scol),
                (lptr_t)(smV + tid*8 + c*2048), 16, 0, 0);
        }
        __syncthreads();

        if (k0 > q0w + 31) continue;

        // S^T: st[mt][nt], lane holds S[q=q0w+nt*16+l15][k=k0+mt*16+quad*4+r]
        float4v st[4][2];
#pragma unroll
        for (int mt = 0; mt < 4; mt++)
#pragma unroll
            for (int nt = 0; nt < 2; nt++)
#pragma unroll
                for (int r = 0; r < 4; r++) st[mt][nt][r] = 0.f;
#pragma unroll
        for (int c = 0; c < 2; c++)
#pragma unroll
            for (int mt = 0; mt < 4; mt++) {
                short8 ak = *(const short8*)(smK + (mt*16 + l15)*64 + ((c*4 + quad) ^ l7)*8);
                st[mt][0] = __builtin_amdgcn_mfma_f32_16x16x32_bf16(ak, bq[0][c], st[mt][0], 0, 0, 0);
                st[mt][1] = __builtin_amdgcn_mfma_f32_16x16x32_bf16(ak, bq[1][c], st[mt][1], 0, 0, 0);
            }

        // mask near-diagonal tiles only
        if (k0 + 63 > q0w) {
#pragma unroll
            for (int mt = 0; mt < 4; mt++)
#pragma unroll
                for (int nt = 0; nt < 2; nt++) {
                    int qn = q0w + nt*16 + l15;
#pragma unroll
                    for (int r = 0; r < 4; r++) {
                        int kg = k0 + mt*16 + quad*4 + r;
                        if (kg > qn) st[mt][nt][r] = -1e30f;
                    }
                }
        }

        // fixed-bias softmax: p = exp2(s - SBIAS); no max, no rescale
#pragma unroll
        for (int nt = 0; nt < 2; nt++) {
            float rs = 0.f;
#pragma unroll
            for (int mt = 0; mt < 4; mt++) {
                float p0 = exp2f(st[mt][nt][0] - SBIAS);
                float p1 = exp2f(st[mt][nt][1] - SBIAS);
                float p2 = exp2f(st[mt][nt][2] - SBIAS);
                float p3 = exp2f(st[mt][nt][3] - SBIAS);
                rs += (p0 + p1) + (p2 + p3);
                short4v pk;
                pk[0] = f2bs(p0); pk[1] = f2bs(p1);
                pk[2] = f2bs(p2); pk[3] = f2bs(p3);
                *(short4v*)(P + (nt*16 + l15)*PSTR + mt*16 + quad*4) = pk;
            }
            rs += __shfl_xor(rs, 16);
            rs += __shfl_xor(rs, 32);
            lsum[nt] += rs;
        }

        short8 bp[2][2];
#pragma unroll
        for (int nt = 0; nt < 2; nt++)
#pragma unroll
            for (int c2 = 0; c2 < 2; c2++)
                bp[nt][c2] = *(const short8*)(P + (nt*16 + l15)*PSTR + c2*32 + quad*8);

        // O^T += V^T-frag * P-frag (pure accumulation, never rescaled)
#pragma unroll
        for (int c2 = 0; c2 < 2; c2++)
#pragma unroll
            for (int mt = 0; mt < 4; mt++) {
                short8 av = *(const short8*)(smV + (mt*16 + l15)*64 + ((c2*4 + quad) ^ l7)*8);
                ot[mt][0] = __builtin_amdgcn_mfma_f32_16x16x32_bf16(av, bp[0][c2], ot[mt][0], 0, 0, 0);
                ot[mt][1] = __builtin_amdgcn_mfma_f32_16x16x32_bf16(av, bp[1][c2], ot[mt][1], 0, 0, 0);
            }
    }

    if (part >= 0) {
        // half job: write unnormalized fp32 partials + lsum
        const int qs = qt - 8;
        float* PO = POb + (size_t)((bh*8 + qs)*2 + part) * 128 * 64;
        float* PL = PLs + (size_t)((bh*8 + qs)*2 + part) * 128;
#pragma unroll
        for (int nt = 0; nt < 2; nt++) {
            const int r = wid*32 + nt*16 + l15;     // row within q-tile
            if (quad == 0) PL[r] = lsum[nt];
#pragma unroll
            for (int mt = 0; mt < 4; mt++)
                *(float4v*)(PO + (size_t)r*64 + mt*16 + quad*4) = ot[mt][nt];
        }
    } else {
        const int b = bh >> 4, h = bh & 15;
#pragma unroll
        for (int nt = 0; nt < 2; nt++) {
            const float inv = 1.0f / lsum[nt];
            const int qn = q0w + nt*16 + l15;
            const size_t rowbase = (size_t)((b*TSZ + qn)*NH + h) * HD;
#pragma unroll
            for (int mt = 0; mt < 4; mt++) {
                short4v pk;
                pk[0] = f2bs(ot[mt][nt][0] * inv); pk[1] = f2bs(ot[mt][nt][1] * inv);
                pk[2] = f2bs(ot[mt][nt][2] * inv); pk[3] = f2bs(ot[mt][nt][3] * inv);
                *(short4v*)(Ob + rowbase + mt*16 + quad*4) = pk;
            }
        }
    }
}

// ---------------------------------------------------------------------------
// Merge the split-tile halves: Ob = (O0+O1)/(l0+l1).
// 64 bh * 8 qs * 128 rows * 16 thr/row = 1,048,576 threads = 4096 blocks.
// (R1 bug: launched 512 blocks -> only bh 0..7 merged, rest garbage.)
// ---------------------------------------------------------------------------
__global__ __launch_bounds__(256) void attn_merge(
    const float* __restrict__ POb, const float* __restrict__ PLs,
    __hip_bfloat16* __restrict__ Ob)
{
    const int i = blockIdx.x * 256 + threadIdx.x;   // 0..1048575
    const int rg  = i >> 4;          // (bh*8+qs)*128 + r, 0..65535
    const int dc  = (i & 15) * 4;
    const int grp = rg >> 7;         // bh*8+qs, 0..511
    const int r   = rg & 127;

    const float4v p0 = *(const float4v*)(POb + ((size_t)(grp*2 + 0)*128 + r)*64 + dc);
    const float4v p1 = *(const float4v*)(POb + ((size_t)(grp*2 + 1)*128 + r)*64 + dc);
    const float l = PLs[(grp*2 + 0)*128 + r] + PLs[(grp*2 + 1)*128 + r];
    const float inv = 1.0f / l;

    const int bh = grp >> 3, qs = grp & 7;
    const int b = bh >> 4, h = bh & 15;
    const int qn = (8 + qs)*128 + r;

    short4v pk;
    pk[0] = f2bs((p0[0] + p1[0]) * inv);
    pk[1] = f2bs((p0[1] + p1[1]) * inv);
    pk[2] = f2bs((p0[2] + p1[2]) * inv);
    pk[3] = f2bs((p0[3] + p1[3]) * inv);
    *(short4v*)(Ob + (size_t)((b*TSZ + qn)*NH + h)*HD + dc) = pk;
}

// ---------------------------------------------------------------------------
// Fallback attention (v4, proven): used only if workspace is too small for
// the split-path partial buffers.
// ---------------------------------------------------------------------------
__global__ __launch_bounds__(256, 2) void attn(
    const __hip_bfloat16* __restrict__ Qb,
    const __hip_bfloat16* __restrict__ Kb,
    const __hip_bfloat16* __restrict__ Vt,
    __hip_bfloat16* __restrict__ Ob)
{
    __shared__ __hip_bfloat16 smK[64*64];
    __shared__ __hip_bfloat16 smV[64*64];
    __shared__ __hip_bfloat16 Pl[4][32*PSTR];

    const int qperm[16] = {15,14,13,12,8,9,10,11,4,5,6,7,3,2,1,0};
    const int bh = blockIdx.x;
    const int qt = qperm[blockIdx.y];
    const int q0 = qt * 128;
    const int tid = threadIdx.x;
    const int wid = tid >> 6, lane = tid & 63;
    const int quad = lane >> 4, l15 = lane & 15;
    const int l7 = l15 & 7;
    const int q0w = q0 + wid * 32;

    const __hip_bfloat16* Qp = Qb + (size_t)bh * TSZ * HD;
    const __hip_bfloat16* Kp = Kb + (size_t)bh * TSZ * HD;
    const __hip_bfloat16* Vp = Vt + (size_t)bh * HD * TSZ;
    __hip_bfloat16* P = &Pl[wid][0];

    const int srow = tid >> 3;
    const int scol = ((tid & 7) ^ (srow & 7)) * 8;

    short8 bq[2][2];
#pragma unroll
    for (int nt = 0; nt < 2; nt++)
#pragma unroll
        for (int c = 0; c < 2; c++)
            bq[nt][c] = *(const short8*)(Qp + (size_t)(q0w + nt*16 + l15)*HD + c*32 + quad*8);

    float lsum[2] = {0.f, 0.f};
    float4v ot[4][2];
#pragma unroll
    for (int mt = 0; mt < 4; mt++)
#pragma unroll
        for (int nt = 0; nt < 2; nt++)
#pragma unroll
            for (int r = 0; r < 4; r++) ot[mt][nt][r] = 0.f;

    const int ntb = 2*qt + 2;
    for (int it = 0; it < ntb; ++it) {
        const int k0 = it * 64;

        __syncthreads();
#pragma unroll
        for (int c = 0; c < 2; c++) {
            __builtin_amdgcn_global_load_lds(
                (gptr_t)(Kp + (size_t)(k0 + srow + 32*c)*HD + scol),
                (lptr_t)(smK + tid*8 + c*2048), 16, 0, 0);
            __builtin_amdgcn_global_load_lds(
                (gptr_t)(Vp + (size_t)(srow + 32*c)*TSZ + k0 + scol),
                (lptr_t)(smV + tid*8 + c*2048), 16, 0, 0);
        }
        __syncthreads();

        if (k0 > q0w + 31) continue;

        float4v st[4][2];
#pragma unroll
        for (int mt = 0; mt < 4; mt++)
#pragma unroll
            for (int nt = 0; nt < 2; nt++)
#pragma unroll
                for (int r = 0; r < 4; r++) st[mt][nt][r] = 0.f;
#pragma unroll
        for (int c = 0; c < 2; c++)
#pragma unroll
            for (int mt = 0; mt < 4; mt++) {
                short8 ak = *(const short8*)(smK + (mt*16 + l15)*64 + ((c*4 + quad) ^ l7)*8);
                st[mt][0] = __builtin_amdgcn_mfma_f32_16x16x32_bf16(ak, bq[0][c], st[mt][0], 0, 0, 0);
                st[mt][1] = __builtin_amdgcn_mfma_f32_16x16x32_bf16(ak, bq[1][c], st[mt][1], 0, 0, 0);
            }

        if (k0 + 63 > q0w) {
#pragma unroll
            for (int mt = 0; mt < 4; mt++)
#pragma unroll
                for (int nt = 0; nt < 2; nt++) {
                    int qn = q0w + nt*16 + l15;
#pragma unroll
                    for (int r = 0; r < 4; r++) {
                        int kg = k0 + mt*16 + quad*4 + r;
                        if (kg > qn) st[mt][nt][r] = -1e30f;
                    }
                }
        }

#pragma unroll
        for (int nt = 0; nt < 2; nt++) {
            float rs = 0.f;
#pragma unroll
            for (int mt = 0; mt < 4; mt++) {
                float p0 = exp2f(st[mt][nt][0] - SBIAS);
                float p1 = exp2f(st[mt][nt][1] - SBIAS);
                float p2 = exp2f(st[mt][nt][2] - SBIAS);
                float p3 = exp2f(st[mt][nt][3] - SBIAS);
                rs += (p0 + p1) + (p2 + p3);
                short4v pk;
                pk[0] = f2bs(p0); pk[1] = f2bs(p1);
                pk[2] = f2bs(p2); pk[3] = f2bs(p3);
                *(short4v*)(P + (nt*16 + l15)*PSTR + mt*16 + quad*4) = pk;
            }
            rs += __shfl_xor(rs, 16);
            rs += __shfl_xor(rs, 32);
            lsum[nt] += rs;
        }

        short8 bp[2][2];
#pragma unroll
        for (int nt = 0; nt < 2; nt++)
#pragma unroll
            for (int c2 = 0; c2 < 2; c2++)
                bp[nt][c2] = *(const short8*)(P + (nt*16 + l15)*PSTR + c2*32 + quad*8);

#pragma unroll
        for (int c2 = 0; c2 < 2; c2++)
#pragma unroll
            for (int mt = 0; mt < 4; mt++) {
                short8 av = *(const short8*)(smV + (mt*16 + l15)*64 + ((c2*4 + quad) ^ l7)*8);
                ot[mt][0] = __builtin_amdgcn_mfma_f32_16x16x32_bf16(av, bp[0][c2], ot[mt][0], 0, 0, 0);
                ot[mt][1] = __builtin_amdgcn_mfma_f32_16x16x32_bf16(av, bp[1][c2], ot[mt][1], 0, 0, 0);
            }
    }

    const int b = bh >> 4, h = bh & 15;
#pragma unroll
    for (int nt = 0; nt < 2; nt++) {
        const float inv = 1.0f / lsum[nt];
        const int qn = q0w + nt*16 + l15;
        const size_t rowbase = (size_t)((b*TSZ + qn)*NH + h) * HD;
#pragma unroll
        for (int mt = 0; mt < 4; mt++) {
            short4v pk;
            pk[0] = f2bs(ot[mt][nt][0] * inv); pk[1] = f2bs(ot[mt][nt][1] * inv);
            pk[2] = f2bs(ot[mt][nt][2] * inv); pk[3] = f2bs(ot[mt][nt][3] * inv);
            *(short4v*)(Ob + rowbase + mt*16 + quad*4) = pk;
        }
    }
}

// ---------------------------------------------------------------------------
// Output projection: out = Ob @ wo^T (bf16 x bf16 -> fp32). grid = (64, 8).
// ---------------------------------------------------------------------------
__global__ __launch_bounds__(256) void out_gemm(
    const __hip_bfloat16* __restrict__ A,
    const __hip_bfloat16* __restrict__ w,
    float* __restrict__ out)
{
    __shared__ __hip_bfloat16 smA[128*64];
    __shared__ __hip_bfloat16 smB[128*64];

    const int tid = threadIdx.x;
    const int wid = tid >> 6, lane = tid & 63;
    const int quad = lane >> 4, l15 = lane & 15;
    const int m0 = blockIdx.x * 128, n0 = blockIdx.y * 128;
    const int wm0 = m0 + (wid >> 1) * 64;
    const int wn0 = n0 + (wid & 1) * 64;

    float4v acc[4][4];
#pragma unroll
    for (int i = 0; i < 4; i++)
#pragma unroll
        for (int j = 0; j < 4; j++)
#pragma unroll
            for (int r = 0; r < 4; r++) acc[i][j][r] = 0.0f;

    gemm_core(A, w, smA, smB, m0, n0, tid, acc);

#pragma unroll
    for (int mb = 0; mb < 4; mb++)
#pragma unroll
        for (int nb = 0; nb < 4; nb++)
#pragma unroll
            for (int r = 0; r < 4; r++) {
                int m = wm0 + mb*16 + quad*4 + r;
                int n = wn0 + nb*16 + l15;
                out[(size_t)m*DIM + n] = acc[mb][nb][r];
            }
}

// ---------------------------------------------------------------------------
extern "C" void kernel_launch(void* const* d_in, const int* in_sizes, int n_in,
                              void* d_out, int out_size, void* d_ws, size_t ws_size,
                              hipStream_t stream) {
    const float* x  = (const float*)d_in[0];
    // d_in[1] = mask — causal structure applied analytically in-kernel
    const float* wq = (const float*)d_in[2];
    const float* wk = (const float*)d_in[3];
    const float* wv = (const float*)d_in[4];
    const float* wo = (const float*)d_in[5];
    float* out = (float*)d_out;

    char* ws = (char*)d_ws;
    const size_t MB = (size_t)1024 * 1024;
    __hip_bfloat16* Qb  = (__hip_bfloat16*)(ws);            // 16 MB [64][2048][64]
    __hip_bfloat16* Kb  = (__hip_bfloat16*)(ws + 16*MB);    // 16 MB [64][2048][64]
    __hip_bfloat16* Vt  = (__hip_bfloat16*)(ws + 32*MB);    // 16 MB [64][64][2048]
    __hip_bfloat16* xb  = (__hip_bfloat16*)(ws + 48*MB);    // 16 MB (aliased w/ Ob)
    __hip_bfloat16* Ob  = (__hip_bfloat16*)(ws + 48*MB);    // x dead before attn
    __hip_bfloat16* wqb = (__hip_bfloat16*)(ws + 64*MB);    // 2 MB
    __hip_bfloat16* wkb = (__hip_bfloat16*)(ws + 66*MB);    // 2 MB
    __hip_bfloat16* wvb = (__hip_bfloat16*)(ws + 68*MB);    // 2 MB
    __hip_bfloat16* wob = (__hip_bfloat16*)(ws + 70*MB);    // 2 MB
    float* POb = (float*)(ws + 72*MB);                      // 32 MB fp32 partial O
    float* PLs = (float*)(ws + 106*MB);                     // 0.5 MB fp32 partial lsum
    const bool use_split = ws_size >= 107*MB;

    dim3 blk(256);
    cvt_kernel<<<dim3(8192 + 4*1024), blk, 0, stream>>>(
        x, wq, wk, wv, wo, xb, wqb, wkb, wvb, wob);
    qkv_gemm<<<dim3(BT/128, DIM/128, 3), blk, 0, stream>>>(
        xb, wqb, wkb, wvb, Qb, Kb, Vt);
    if (use_split) {
        attn_split<<<dim3(BSZ*NH, 24), blk, 0, stream>>>(Qb, Kb, Vt, Ob, POb, PLs);
        attn_merge<<<dim3(4096), blk, 0, stream>>>(POb, PLs, Ob);
    } else {
        attn<<<dim3(BSZ*NH, 16), blk, 0, stream>>>(Qb, Kb, Vt, Ob);
    }
    out_gemm<<<dim3(BT/128, DIM/128), blk, 0, stream>>>(Ob, wob, out);
}

// Round 3
// 246.523 us; speedup vs baseline: 1.0542x; 1.0542x over previous
//
#include <hip/hip_runtime.h>
#include <hip/hip_bf16.h>

typedef __attribute__((ext_vector_type(8))) short short8;
typedef __attribute__((ext_vector_type(4))) short short4v;
typedef __attribute__((ext_vector_type(4))) float float4v;

#define DIM   1024
#define NH    16
#define HD    64
#define BSZ   4
#define TSZ   2048
#define BT    (BSZ*TSZ)   // 8192

// softmax exponent bias: |s| <= |q||k|*0.18 ~ 12 << 24; exp2(s-24) never
// overflows, never fully underflows (needs s < -102). Softmax shift-invariant
// -> dividing by lsum reproduces reference exactly. Kills online rescaling.
// Folded into the QK^T MFMA accumulator init (C = -SBIAS) -> zero VALU cost.
#define SBIAS 24.0f

// P tile in LDS: 32 rows x 64 cols bf16 per wave, XOR-swizzled (elem ^=
// (row&7)<<3) instead of padded. 4KB/wave -> total LDS = 32768 B exactly
// -> 5 blocks/CU (was 34816 B -> 4 blocks/CU). Swizzle keeps 8B writes and
// 16B reads aligned and bank-uniform (8 lanes per 4-bank group = b128 min).
#define PIDX(row, col) ((((row)*64 + (col)) ^ (((row)&7) << 3)))

typedef const __attribute__((address_space(1))) void* gptr_t;
typedef __attribute__((address_space(3))) void* lptr_t;

__device__ __forceinline__ short f2bs(float x) {
    __hip_bfloat16 h = __float2bfloat16(x);
    return __builtin_bit_cast(short, h);
}

// ---------------------------------------------------------------------------
// fp32 -> bf16 conversion: x (8192 blocks) + wq/wk/wv/wo (1024 blocks each).
// ---------------------------------------------------------------------------
__global__ __launch_bounds__(256) void cvt_kernel(
    const float* __restrict__ x,  const float* __restrict__ wq,
    const float* __restrict__ wk, const float* __restrict__ wv,
    const float* __restrict__ wo,
    __hip_bfloat16* __restrict__ xb,  __hip_bfloat16* __restrict__ wqb,
    __hip_bfloat16* __restrict__ wkb, __hip_bfloat16* __restrict__ wvb,
    __hip_bfloat16* __restrict__ wob)
{
    int bid = blockIdx.x;
    const float* src; __hip_bfloat16* dst; int base;
    if (bid < 8192) { src = x; dst = xb; base = bid; }
    else {
        int wsel = (bid - 8192) >> 10;
        base = (bid - 8192) & 1023;
        src = (wsel == 0) ? wq : (wsel == 1) ? wk : (wsel == 2) ? wv : wo;
        dst = (wsel == 0) ? wqb : (wsel == 1) ? wkb : (wsel == 2) ? wvb : wob;
    }
    size_t off = (size_t)base * 1024 + threadIdx.x * 4;
    float4v v = *(const float4v*)(src + off);
    short4v o;
    o[0] = f2bs(v[0]); o[1] = f2bs(v[1]); o[2] = f2bs(v[2]); o[3] = f2bs(v[3]);
    *(short4v*)((short*)dst + off) = o;
}

// ---------------------------------------------------------------------------
// gemm_core v2: 128x128 tile, BK=64 (16 iters, 32 MFMA/barrier), XOR-swizzled
// staging so ds_read_b128 frag reads are 2-way (free) instead of 8-way.
// ---------------------------------------------------------------------------
__device__ __forceinline__ void gemm_core(
    const __hip_bfloat16* __restrict__ A,
    const __hip_bfloat16* __restrict__ B,
    __hip_bfloat16* smA, __hip_bfloat16* smB,
    int m0, int n0, int tid, float4v acc[4][4])
{
    const int wid = tid >> 6, lane = tid & 63;
    const int quad = lane >> 4, l15 = lane & 15;
    const int l7 = l15 & 7;
    const int wm = (wid >> 1) * 64, wn = (wid & 1) * 64;
    const int srow = tid >> 3;                        // 0..31
    const int scol = ((tid & 7) ^ (srow & 7)) * 8;    // swizzled source chunk

    const __hip_bfloat16* gA0 = A + (size_t)(m0 + srow) * DIM + scol;
    const __hip_bfloat16* gB0 = B + (size_t)(n0 + srow) * DIM + scol;

    for (int kc = 0; kc < DIM; kc += 64) {
        __syncthreads();
#pragma unroll
        for (int j = 0; j < 4; j++) {
            __builtin_amdgcn_global_load_lds((gptr_t)(gA0 + (size_t)(j*32)*DIM + kc),
                (lptr_t)(smA + j*2048 + tid*8), 16, 0, 0);
            __builtin_amdgcn_global_load_lds((gptr_t)(gB0 + (size_t)(j*32)*DIM + kc),
                (lptr_t)(smB + j*2048 + tid*8), 16, 0, 0);
        }
        __syncthreads();

#pragma unroll
        for (int s = 0; s < 2; s++) {
            short8 a[4], b[4];
#pragma unroll
            for (int mb = 0; mb < 4; mb++)
                a[mb] = *(const short8*)(smA + (wm + mb*16 + l15)*64 + ((s*4 + quad) ^ l7)*8);
#pragma unroll
            for (int nb = 0; nb < 4; nb++)
                b[nb] = *(const short8*)(smB + (wn + nb*16 + l15)*64 + ((s*4 + quad) ^ l7)*8);
#pragma unroll
            for (int mb = 0; mb < 4; mb++)
#pragma unroll
                for (int nb = 0; nb < 4; nb++)
                    acc[mb][nb] = __builtin_amdgcn_mfma_f32_16x16x32_bf16(
                        a[mb], b[nb], acc[mb][nb], 0, 0, 0);
        }
    }
}

// ---------------------------------------------------------------------------
// QKV projection. Q pre-scaled by 0.125*log2(e) -> softmax in exp2 domain.
// ---------------------------------------------------------------------------
__global__ __launch_bounds__(256) void qkv_gemm(
    const __hip_bfloat16* __restrict__ xb,
    const __hip_bfloat16* __restrict__ wqb,
    const __hip_bfloat16* __restrict__ wkb,
    const __hip_bfloat16* __restrict__ wvb,
    __hip_bfloat16* __restrict__ Qb,
    __hip_bfloat16* __restrict__ Kb,
    __hip_bfloat16* __restrict__ Vt)
{
    __shared__ __hip_bfloat16 smA[128*64];
    __shared__ __hip_bfloat16 smB[128*64];

    const int z = blockIdx.z;
    const __hip_bfloat16* w = (z == 0) ? wqb : ((z == 1) ? wkb : wvb);
    const int tid = threadIdx.x;
    const int wid = tid >> 6, lane = tid & 63;
    const int quad = lane >> 4, l15 = lane & 15;
    const int m0 = blockIdx.x * 128, n0 = blockIdx.y * 128;
    const int wm0 = m0 + (wid >> 1) * 64;
    const int wn0 = n0 + (wid & 1) * 64;
    const float qscale = 0.1803368801111204f;  // 0.125 * log2(e)

    float4v acc[4][4];
#pragma unroll
    for (int i = 0; i < 4; i++)
#pragma unroll
        for (int j = 0; j < 4; j++)
#pragma unroll
            for (int r = 0; r < 4; r++) acc[i][j][r] = 0.0f;

    gemm_core(xb, w, smA, smB, m0, n0, tid, acc);

    if (z == 2) {
        const int h = wn0 >> 6;
#pragma unroll
        for (int mb = 0; mb < 4; mb++) {
            int m = wm0 + mb*16 + quad*4;
            int bb = m >> 11, t0 = m & 2047;
#pragma unroll
            for (int nb = 0; nb < 4; nb++) {
                int d = nb*16 + l15;
                short4v pk;
                pk[0] = f2bs(acc[mb][nb][0]); pk[1] = f2bs(acc[mb][nb][1]);
                pk[2] = f2bs(acc[mb][nb][2]); pk[3] = f2bs(acc[mb][nb][3]);
                *(short4v*)(Vt + (size_t)((bb*NH + h)*HD + d)*TSZ + t0) = pk;
            }
        }
    } else {
        const float sc = (z == 0) ? qscale : 1.0f;
        __hip_bfloat16* dst = (z == 0) ? Qb : Kb;
#pragma unroll
        for (int mb = 0; mb < 4; mb++)
#pragma unroll
            for (int r = 0; r < 4; r++) {
                int m = wm0 + mb*16 + quad*4 + r;
                int bb = m >> 11, t = m & 2047;
#pragma unroll
                for (int nb = 0; nb < 4; nb++) {
                    int n = wn0 + nb*16 + l15;
                    int h = n >> 6, d = n & 63;
                    dst[(size_t)((bb*NH + h)*TSZ + t)*HD + d] =
                        __float2bfloat16(acc[mb][nb][r] * sc);
                }
            }
    }
}

// ---------------------------------------------------------------------------
// Causal flash attention v6. R2 evidence: kernel is per-CU throughput/latency
// bound (split-balancing changed nothing), 4 waves/SIMD can't fill the pipes
// (VALU 55%, MFMA 19%, none saturated). Changes:
//   1. LDS 34816 -> 32768 B exactly (P: PSTR72 pad -> 64 + XOR swizzle)
//      => 5 blocks/CU instead of 4 (+25% waves/SIMD).
//   2. -SBIAS folded into QK^T accumulator C-init (kills 32 v_sub/wave-tile).
//   3. lsum cross-lane reduce deferred to epilogue (kills 4 shfl+4 add/tile;
//      valid because lsum is a pure order-free sum - no rescaling ever).
//   4. Wave-uniform per-mt mask guard (halves diagonal-tile cmp/cndmask).
// ---------------------------------------------------------------------------
__global__ __launch_bounds__(256, 2) void attn(
    const __hip_bfloat16* __restrict__ Qb,
    const __hip_bfloat16* __restrict__ Kb,
    const __hip_bfloat16* __restrict__ Vt,
    __hip_bfloat16* __restrict__ Ob)
{
    __shared__ __hip_bfloat16 smK[64*64];       // 8KB [k-row][d], XOR-swizzled
    __shared__ __hip_bfloat16 smV[64*64];       // 8KB [d][t],     XOR-swizzled
    __shared__ __hip_bfloat16 Pl[4][32*64];     // 16KB per-wave P, XOR-swizzled

    const int qperm[16] = {15,14,13,12,8,9,10,11,4,5,6,7,3,2,1,0};
    const int bh = blockIdx.x;
    const int qt = qperm[blockIdx.y];
    const int q0 = qt * 128;
    const int tid = threadIdx.x;
    const int wid = tid >> 6, lane = tid & 63;
    const int quad = lane >> 4, l15 = lane & 15;
    const int l7 = l15 & 7;
    const int q0w = q0 + wid * 32;

    const __hip_bfloat16* Qp = Qb + (size_t)bh * TSZ * HD;
    const __hip_bfloat16* Kp = Kb + (size_t)bh * TSZ * HD;
    const __hip_bfloat16* Vp = Vt + (size_t)bh * HD * TSZ;
    __hip_bfloat16* P = &Pl[wid][0];

    const int srow = tid >> 3;
    const int scol = ((tid & 7) ^ (srow & 7)) * 8;

    short8 bq[2][2];
#pragma unroll
    for (int nt = 0; nt < 2; nt++)
#pragma unroll
        for (int c = 0; c < 2; c++)
            bq[nt][c] = *(const short8*)(Qp + (size_t)(q0w + nt*16 + l15)*HD + c*32 + quad*8);

    float lsum[2] = {0.f, 0.f};   // per-lane partial; cross-quad reduce at end
    float4v ot[4][2];
#pragma unroll
    for (int mt = 0; mt < 4; mt++)
#pragma unroll
        for (int nt = 0; nt < 2; nt++)
#pragma unroll
            for (int r = 0; r < 4; r++) ot[mt][nt][r] = 0.f;

    const int ntb = 2*qt + 2;
    for (int it = 0; it < ntb; ++it) {
        const int k0 = it * 64;

        __syncthreads();
#pragma unroll
        for (int c = 0; c < 2; c++) {
            __builtin_amdgcn_global_load_lds(
                (gptr_t)(Kp + (size_t)(k0 + srow + 32*c)*HD + scol),
                (lptr_t)(smK + tid*8 + c*2048), 16, 0, 0);
            __builtin_amdgcn_global_load_lds(
                (gptr_t)(Vp + (size_t)(srow + 32*c)*TSZ + k0 + scol),
                (lptr_t)(smV + tid*8 + c*2048), 16, 0, 0);
        }
        __syncthreads();

        if (k0 > q0w + 31) continue;

        // S^T - SBIAS: st[mt][nt], lane holds S[q=q0w+nt*16+l15][k=k0+mt*16+quad*4+r]
        // SBIAS folded into C-init: exp2f(st) directly, no per-element sub.
        float4v st[4][2];
#pragma unroll
        for (int mt = 0; mt < 4; mt++)
#pragma unroll
            for (int nt = 0; nt < 2; nt++)
#pragma unroll
                for (int r = 0; r < 4; r++) st[mt][nt][r] = -SBIAS;
#pragma unroll
        for (int c = 0; c < 2; c++)
#pragma unroll
            for (int mt = 0; mt < 4; mt++) {
                short8 ak = *(const short8*)(smK + (mt*16 + l15)*64 + ((c*4 + quad) ^ l7)*8);
                st[mt][0] = __builtin_amdgcn_mfma_f32_16x16x32_bf16(ak, bq[0][c], st[mt][0], 0, 0, 0);
                st[mt][1] = __builtin_amdgcn_mfma_f32_16x16x32_bf16(ak, bq[1][c], st[mt][1], 0, 0, 0);
            }

        // mask near-diagonal tiles only; per-mt guard is wave-uniform
        if (k0 + 63 > q0w) {
#pragma unroll
            for (int mt = 0; mt < 4; mt++) {
                if (k0 + mt*16 + 15 > q0w) {
#pragma unroll
                    for (int nt = 0; nt < 2; nt++) {
                        int qn = q0w + nt*16 + l15;
#pragma unroll
                        for (int r = 0; r < 4; r++) {
                            int kg = k0 + mt*16 + quad*4 + r;
                            if (kg > qn) st[mt][nt][r] = -1e30f;
                        }
                    }
                }
            }
        }

        // fixed-bias softmax: p = exp2(st); no max, no rescale, no reduce here
#pragma unroll
        for (int nt = 0; nt < 2; nt++) {
            float rs = 0.f;
#pragma unroll
            for (int mt = 0; mt < 4; mt++) {
                float p0 = exp2f(st[mt][nt][0]);
                float p1 = exp2f(st[mt][nt][1]);
                float p2 = exp2f(st[mt][nt][2]);
                float p3 = exp2f(st[mt][nt][3]);
                rs += (p0 + p1) + (p2 + p3);
                short4v pk;
                pk[0] = f2bs(p0); pk[1] = f2bs(p1);
                pk[2] = f2bs(p2); pk[3] = f2bs(p3);
                *(short4v*)(P + PIDX(nt*16 + l15, mt*16 + quad*4)) = pk;
            }
            lsum[nt] += rs;   // per-lane partial only
        }

        short8 bp[2][2];
#pragma unroll
        for (int nt = 0; nt < 2; nt++)
#pragma unroll
            for (int c2 = 0; c2 < 2; c2++)
                bp[nt][c2] = *(const short8*)(P + PIDX(nt*16 + l15, c2*32 + quad*8));

        // O^T += V^T-frag * P-frag (pure accumulation, never rescaled)
#pragma unroll
        for (int c2 = 0; c2 < 2; c2++)
#pragma unroll
            for (int mt = 0; mt < 4; mt++) {
                short8 av = *(const short8*)(smV + (mt*16 + l15)*64 + ((c2*4 + quad) ^ l7)*8);
                ot[mt][0] = __builtin_amdgcn_mfma_f32_16x16x32_bf16(av, bp[0][c2], ot[mt][0], 0, 0, 0);
                ot[mt][1] = __builtin_amdgcn_mfma_f32_16x16x32_bf16(av, bp[1][c2], ot[mt][1], 0, 0, 0);
            }
    }

    const int b = bh >> 4, h = bh & 15;
#pragma unroll
    for (int nt = 0; nt < 2; nt++) {
        // complete the row sum across the 4 quads (deferred from the loop)
        float ls = lsum[nt];
        ls += __shfl_xor(ls, 16);
        ls += __shfl_xor(ls, 32);
        const float inv = 1.0f / ls;
        const int qn = q0w + nt*16 + l15;
        const size_t rowbase = (size_t)((b*TSZ + qn)*NH + h) * HD;
#pragma unroll
        for (int mt = 0; mt < 4; mt++) {
            short4v pk;
            pk[0] = f2bs(ot[mt][nt][0] * inv); pk[1] = f2bs(ot[mt][nt][1] * inv);
            pk[2] = f2bs(ot[mt][nt][2] * inv); pk[3] = f2bs(ot[mt][nt][3] * inv);
            *(short4v*)(Ob + rowbase + mt*16 + quad*4) = pk;
        }
    }
}

// ---------------------------------------------------------------------------
// Output projection: out = Ob @ wo^T (bf16 x bf16 -> fp32). grid = (64, 8).
// ---------------------------------------------------------------------------
__global__ __launch_bounds__(256) void out_gemm(
    const __hip_bfloat16* __restrict__ A,
    const __hip_bfloat16* __restrict__ w,
    float* __restrict__ out)
{
    __shared__ __hip_bfloat16 smA[128*64];
    __shared__ __hip_bfloat16 smB[128*64];

    const int tid = threadIdx.x;
    const int wid = tid >> 6, lane = tid & 63;
    const int quad = lane >> 4, l15 = lane & 15;
    const int m0 = blockIdx.x * 128, n0 = blockIdx.y * 128;
    const int wm0 = m0 + (wid >> 1) * 64;
    const int wn0 = n0 + (wid & 1) * 64;

    float4v acc[4][4];
#pragma unroll
    for (int i = 0; i < 4; i++)
#pragma unroll
        for (int j = 0; j < 4; j++)
#pragma unroll
            for (int r = 0; r < 4; r++) acc[i][j][r] = 0.0f;

    gemm_core(A, w, smA, smB, m0, n0, tid, acc);

#pragma unroll
    for (int mb = 0; mb < 4; mb++)
#pragma unroll
        for (int nb = 0; nb < 4; nb++)
#pragma unroll
            for (int r = 0; r < 4; r++) {
                int m = wm0 + mb*16 + quad*4 + r;
                int n = wn0 + nb*16 + l15;
                out[(size_t)m*DIM + n] = acc[mb][nb][r];
            }
}

// ---------------------------------------------------------------------------
extern "C" void kernel_launch(void* const* d_in, const int* in_sizes, int n_in,
                              void* d_out, int out_size, void* d_ws, size_t ws_size,
                              hipStream_t stream) {
    const float* x  = (const float*)d_in[0];
    // d_in[1] = mask — causal structure applied analytically in-kernel
    const float* wq = (const float*)d_in[2];
    const float* wk = (const float*)d_in[3];
    const float* wv = (const float*)d_in[4];
    const float* wo = (const float*)d_in[5];
    float* out = (float*)d_out;

    char* ws = (char*)d_ws;
    const size_t MB = (size_t)1024 * 1024;
    __hip_bfloat16* Qb  = (__hip_bfloat16*)(ws);            // 16 MB [64][2048][64]
    __hip_bfloat16* Kb  = (__hip_bfloat16*)(ws + 16*MB);    // 16 MB [64][2048][64]
    __hip_bfloat16* Vt  = (__hip_bfloat16*)(ws + 32*MB);    // 16 MB [64][64][2048]
    __hip_bfloat16* xb  = (__hip_bfloat16*)(ws + 48*MB);    // 16 MB (aliased w/ Ob)
    __hip_bfloat16* Ob  = (__hip_bfloat16*)(ws + 48*MB);    // x dead before attn
    __hip_bfloat16* wqb = (__hip_bfloat16*)(ws + 64*MB);    // 2 MB
    __hip_bfloat16* wkb = (__hip_bfloat16*)(ws + 66*MB);    // 2 MB
    __hip_bfloat16* wvb = (__hip_bfloat16*)(ws + 68*MB);    // 2 MB
    __hip_bfloat16* wob = (__hip_bfloat16*)(ws + 70*MB);    // 2 MB

    dim3 blk(256);
    cvt_kernel<<<dim3(8192 + 4*1024), blk, 0, stream>>>(
        x, wq, wk, wv, wo, xb, wqb, wkb, wvb, wob);
    qkv_gemm<<<dim3(BT/128, DIM/128, 3), blk, 0, stream>>>(
        xb, wqb, wkb, wvb, Qb, Kb, Vt);
    attn<<<dim3(BSZ*NH, 16), blk, 0, stream>>>(Qb, Kb, Vt, Ob);
    out_gemm<<<dim3(BT/128, DIM/128), blk, 0, stream>>>(Ob, wob, out);
}